// Round 2
// baseline (3700.673 us; speedup 1.0000x reference)
//
#include <hip/hip_runtime.h>
#include <stdint.h>

#define DIMM 1024
#define NSEQ 1024
#define BB 2
#define HEADSN 16
#define MLPD 4096
#define DEPTHN 4
#define MROWS (BB*NSEQ)  // 2048
#define VSTR 10240       // canonical per-layer vec stride (elements)

typedef __bf16 bf16x8 __attribute__((ext_vector_type(8)));
typedef float f32x4 __attribute__((ext_vector_type(4)));

__device__ __forceinline__ float bf2f(unsigned short u) {
    union { uint32_t i; float f; } x; x.i = ((uint32_t)u) << 16; return x.f;
}
__device__ __forceinline__ unsigned short f2bf(float f) {
    union { uint32_t i; float f; } x; x.f = f;
    uint32_t r = x.i + 0x7fffu + ((x.i >> 16) & 1u);
    return (unsigned short)(r >> 16);
}
// dual-dtype scalar load: f32=1 -> fp32 array, f32=0 -> bf16 array (index in elements)
__device__ __forceinline__ float loadf(const void* p, size_t i, int f32) {
    return f32 ? ((const float*)p)[i] : bf2f(((const unsigned short*)p)[i]);
}

// ---------------- dtype sniff ----------------
// If the float tensors are fp32, the EVEN ushort half-words are mantissa noise with
// uniformly random exponent fields; if bf16, every ushort is a sane N(0,1) value.
__global__ __launch_bounds__(256) void sniff_kernel(const unsigned short* __restrict__ x,
                                                    int* __restrict__ flag) {
    __shared__ int cnt[256];
    int tid = threadIdx.x;
    int c = 0;
    for (int i = tid * 2; i < 65536; i += 512) {   // even indices; 128KB < min buffer size
        int e = (x[i] >> 7) & 0xFF;
        if (e >= 0x8A) c++;                        // |v| >= 2^11: impossible for N(0,1) bf16
    }
    cnt[tid] = c;
    __syncthreads();
    for (int s = 128; s > 0; s >>= 1) {
        if (tid < s) cnt[tid] += cnt[tid + s];
        __syncthreads();
    }
    if (tid == 0) flag[0] = (cnt[0] > 32) ? 1 : 0;
}

// ---------------- converts ----------------
__global__ __launch_bounds__(256) void cvt_x(const void* __restrict__ x, float* __restrict__ xf,
                                             const int* __restrict__ flag) {
    int f = flag[0];
    int i = blockIdx.x * 256 + threadIdx.x;
    xf[i] = loadf(x, i, f);
}
__global__ __launch_bounds__(256) void store_out(const float* __restrict__ xf, void* __restrict__ out,
                                                 const int* __restrict__ flag) {
    int f = flag[0];
    int i = blockIdx.x * 256 + threadIdx.x;
    float v = xf[i];
    if (f) ((float*)out)[i] = v;
    else   ((unsigned short*)out)[i] = f2bf(v);
}
// [DEPTH,len] src -> canonical bf16 dst[l*VSTR + j]
__global__ __launch_bounds__(256) void conv_vec(const void* __restrict__ src,
                                                unsigned short* __restrict__ dst,
                                                int len, const int* __restrict__ flag) {
    int f = flag[0];
    int i = blockIdx.x * 256 + threadIdx.x;
    if (i < DEPTHN * len) {
        int l = i / len, o = i - l * len;
        dst[l * VSTR + o] = f2bf(loadf(src, i, f));
    }
}

// ---------------- transpose+convert: src[srcOffE + k*N + n] -> bf16 out[n*K + k] ----------------
__global__ __launch_bounds__(256) void transpose_conv(const void* __restrict__ in, size_t srcOffE,
                                                      unsigned short* __restrict__ out,
                                                      int K, int N, const int* __restrict__ flag) {
    int f = flag[0];
    __shared__ unsigned short t[32][33];
    int n0 = blockIdx.x * 32, k0 = blockIdx.y * 32;
    int tx = threadIdx.x, ty = threadIdx.y;  // 32 x 8
#pragma unroll
    for (int i = 0; i < 4; i++) {
        int k = k0 + ty + i * 8;
        t[ty + i * 8][tx] = f2bf(loadf(in, srcOffE + (size_t)k * N + n0 + tx, f));
    }
    __syncthreads();
#pragma unroll
    for (int i = 0; i < 4; i++) {
        int n = n0 + ty + i * 8;
        out[(size_t)n * K + k0 + tx] = t[tx][ty + i * 8];
    }
}

// ---------------- LayerNorm: fp32 x -> bf16 out ----------------
__global__ __launch_bounds__(256) void ln_kernel(const float* __restrict__ x,
                                                 const unsigned short* __restrict__ g,
                                                 const unsigned short* __restrict__ bta,
                                                 unsigned short* __restrict__ out) {
    int row = blockIdx.x, tid = threadIdx.x;
    const float* xr = x + (size_t)row * DIMM;
    float v[4]; float s = 0.f, s2 = 0.f;
#pragma unroll
    for (int i = 0; i < 4; i++) { v[i] = xr[tid + i * 256]; s += v[i]; s2 += v[i] * v[i]; }
#pragma unroll
    for (int off = 32; off >= 1; off >>= 1) {
        s  += __shfl_down(s, off, 64);
        s2 += __shfl_down(s2, off, 64);
    }
    __shared__ float rs[4], rs2[4];
    int wv = tid >> 6;
    if ((tid & 63) == 0) { rs[wv] = s; rs2[wv] = s2; }
    __syncthreads();
    s  = rs[0] + rs[1] + rs[2] + rs[3];
    s2 = rs2[0] + rs2[1] + rs2[2] + rs2[3];
    float mu  = s * (1.f / DIMM);
    float var = s2 * (1.f / DIMM) - mu * mu;
    float rr  = rsqrtf(var + 1e-5f);
#pragma unroll
    for (int i = 0; i < 4; i++) {
        int c = tid + i * 256;
        float y = (v[i] - mu) * rr * bf2f(g[c]) + bf2f(bta[c]);
        out[(size_t)row * DIMM + c] = f2bf(y);
    }
}

// ---------------- GEMM: A[M,K] bf16 x Bt[N,K] bf16 -> epilogue ----------------
// MODE 0: store bf16 C   MODE 1: Cres(fp32) += acc + bias   MODE 2: bf16 gelu(acc+bias)
template <int MODE>
__global__ __launch_bounds__(256) void gemm_bt(const unsigned short* __restrict__ A,
                                               const unsigned short* __restrict__ Bt,
                                               const unsigned short* __restrict__ bias,
                                               unsigned short* __restrict__ Cbf,
                                               float* __restrict__ Cres,
                                               int M, int N, int K) {
    __shared__ unsigned short As[128 * 32];
    __shared__ unsigned short Bs[128 * 32];
    const int tid = threadIdx.x;
    const int mBase = blockIdx.y * 128, nBase = blockIdx.x * 128;
    const int w = tid >> 6, lane = tid & 63;
    const int wm = (w >> 1) * 64, wn = (w & 1) * 64;
    const int quad = lane >> 4, l16 = lane & 15;
    f32x4 acc[4][4];
#pragma unroll
    for (int i = 0; i < 4; i++)
#pragma unroll
        for (int j = 0; j < 4; j++) acc[i][j] = (f32x4){0.f, 0.f, 0.f, 0.f};

    const int sRow = tid >> 1, sCol = (tid & 1) * 16;
    const unsigned short* Ag = A + (size_t)(mBase + sRow) * K + sCol;
    const unsigned short* Bg = Bt + (size_t)(nBase + sRow) * K + sCol;

    uint4 ra0 = *(const uint4*)(Ag);
    uint4 ra1 = *(const uint4*)(Ag + 8);
    uint4 rb0 = *(const uint4*)(Bg);
    uint4 rb1 = *(const uint4*)(Bg + 8);

    for (int k0 = 0; k0 < K; k0 += 32) {
        __syncthreads();
        *(uint4*)&As[sRow * 32 + sCol]     = ra0;
        *(uint4*)&As[sRow * 32 + sCol + 8] = ra1;
        *(uint4*)&Bs[sRow * 32 + sCol]     = rb0;
        *(uint4*)&Bs[sRow * 32 + sCol + 8] = rb1;
        __syncthreads();
        if (k0 + 32 < K) {
            ra0 = *(const uint4*)(Ag + k0 + 32);
            ra1 = *(const uint4*)(Ag + k0 + 40);
            rb0 = *(const uint4*)(Bg + k0 + 32);
            rb1 = *(const uint4*)(Bg + k0 + 40);
        }
        bf16x8 af[4], bfv[4];
#pragma unroll
        for (int i = 0; i < 4; i++)
            af[i] = *(const bf16x8*)&As[(wm + i * 16 + l16) * 32 + quad * 8];
#pragma unroll
        for (int j = 0; j < 4; j++)
            bfv[j] = *(const bf16x8*)&Bs[(wn + j * 16 + l16) * 32 + quad * 8];
#pragma unroll
        for (int i = 0; i < 4; i++)
#pragma unroll
            for (int j = 0; j < 4; j++)
                acc[i][j] = __builtin_amdgcn_mfma_f32_16x16x32_bf16(af[i], bfv[j], acc[i][j], 0, 0, 0);
    }

#pragma unroll
    for (int i = 0; i < 4; i++) {
#pragma unroll
        for (int j = 0; j < 4; j++) {
#pragma unroll
            for (int r = 0; r < 4; r++) {
                int m = mBase + wm + i * 16 + quad * 4 + r;
                int n = nBase + wn + j * 16 + l16;
                float v = acc[i][j][r];
                size_t idx = (size_t)m * N + n;
                if (MODE == 0) {
                    Cbf[idx] = f2bf(v);
                } else if (MODE == 1) {
                    Cres[idx] += v + bf2f(bias[n]);
                } else {
                    float t2 = v + bf2f(bias[n]);
                    float gg = 0.5f * t2 * (1.f + erff(t2 * 0.70710678118f));
                    Cbf[idx] = f2bf(gg);
                }
            }
        }
    }
}

// ---------------- flash attention: one wave per query row ----------------
__global__ __launch_bounds__(256) void attn_kernel(const unsigned short* __restrict__ qkv,
                                                   const int* __restrict__ mask,
                                                   unsigned short* __restrict__ o) {
    __shared__ unsigned short Ks[64][72];
    __shared__ unsigned short Vs2[64][72];
    __shared__ float qsf[4][68];

    int tid = threadIdx.x, w = tid >> 6, lane = tid & 63;
    int blk = blockIdx.x;
    int qt = blk & 255;
    int h  = (blk >> 8) & 15;
    int b  = blk >> 12;
    int q  = qt * 4 + w;

    const unsigned short* qrow = qkv + ((size_t)(b * NSEQ + q)) * 3072 + h * 64;
    qsf[w][lane] = bf2f(qrow[lane]) * 0.125f;

    float m_run = -1e30f, l_run = 0.f, o_acc = 0.f;
    const int* mrow = mask + ((size_t)b * NSEQ + q) * NSEQ;

    int srow = tid >> 2, dc = (tid & 3) * 16;

    for (int kt = 0; kt < 16; kt++) {
        __syncthreads();
        const unsigned short* kg = qkv + ((size_t)(b * NSEQ + kt * 64 + srow)) * 3072 + 1024 + h * 64 + dc;
        uint4 kv0 = *(const uint4*)kg;
        uint4 kv1 = *(const uint4*)(kg + 8);
        uint4 vv0 = *(const uint4*)(kg + 1024);
        uint4 vv1 = *(const uint4*)(kg + 1032);
        *(uint4*)&Ks[srow][dc]     = kv0;
        *(uint4*)&Ks[srow][dc + 8] = kv1;
        unsigned short tmp[16];
        *(uint4*)&tmp[0] = vv0;
        *(uint4*)&tmp[8] = vv1;
#pragma unroll
        for (int i = 0; i < 16; i++) Vs2[dc + i][srow] = tmp[i];
        __syncthreads();

        float s = 0.f;
        const unsigned short* krow = &Ks[lane][0];
#pragma unroll
        for (int d = 0; d < 64; d += 8) {
            bf16x8 kk = *(const bf16x8*)(krow + d);
            float4 q0 = *(const float4*)&qsf[w][d];
            float4 q1 = *(const float4*)&qsf[w][d + 4];
            s += q0.x * (float)kk[0] + q0.y * (float)kk[1] + q0.z * (float)kk[2] + q0.w * (float)kk[3];
            s += q1.x * (float)kk[4] + q1.y * (float)kk[5] + q1.z * (float)kk[6] + q1.w * (float)kk[7];
        }
        int mv = mrow[kt * 64 + lane];
        s = (mv == 0) ? -1e9f : s;

        float tmax = s;
#pragma unroll
        for (int off = 1; off < 64; off <<= 1) tmax = fmaxf(tmax, __shfl_xor(tmax, off, 64));
        float m_new = fmaxf(m_run, tmax);
        float alpha = __expf(m_run - m_new);
        float p = __expf(s - m_new);
        float psum = p;
#pragma unroll
        for (int off = 1; off < 64; off <<= 1) psum += __shfl_xor(psum, off, 64);
        l_run = l_run * alpha + psum;
        o_acc *= alpha;
        m_run = m_new;

        const unsigned short* vrow = &Vs2[lane][0];
#pragma unroll
        for (int kc = 0; kc < 64; kc += 8) {
            bf16x8 vv = *(const bf16x8*)(vrow + kc);
            o_acc += __shfl(p, kc + 0, 64) * (float)vv[0];
            o_acc += __shfl(p, kc + 1, 64) * (float)vv[1];
            o_acc += __shfl(p, kc + 2, 64) * (float)vv[2];
            o_acc += __shfl(p, kc + 3, 64) * (float)vv[3];
            o_acc += __shfl(p, kc + 4, 64) * (float)vv[4];
            o_acc += __shfl(p, kc + 5, 64) * (float)vv[5];
            o_acc += __shfl(p, kc + 6, 64) * (float)vv[6];
            o_acc += __shfl(p, kc + 7, 64) * (float)vv[7];
        }
    }
    o[((size_t)(b * NSEQ + q)) * 1024 + h * 64 + lane] = f2bf(o_acc / l_run);
}

extern "C" void kernel_launch(void* const* d_in, const int* in_sizes, int n_in,
                              void* d_out, int out_size, void* d_ws, size_t ws_size,
                              hipStream_t stream) {
    const void* x     = d_in[0];
    const int*  mask  = (const int*)d_in[1];
    const void* ln1_g = d_in[2];
    const void* ln1_b = d_in[3];
    const void* qkv_w = d_in[4];
    const void* out_w = d_in[5];
    const void* out_b = d_in[6];
    const void* ln2_g = d_in[7];
    const void* ln2_b = d_in[8];
    const void* ff1_w = d_in[9];
    const void* ff1_b = d_in[10];
    const void* ff2_w = d_in[11];
    const void* ff2_b = d_in[12];

    char* ws = (char*)d_ws;
    float*          xf     = (float*)ws;                           // 8 MB fp32 residual
    unsigned short* h_bf   = (unsigned short*)(ws + (8u  << 20));  // 4 MB LN out
    unsigned short* qkv_bf = (unsigned short*)(ws + (12u << 20));  // 12 MB (attn half)
    unsigned short* ff_bf  = (unsigned short*)(ws + (12u << 20));  // 16 MB (ff half, reuses qkv)
    unsigned short* o_bf   = (unsigned short*)(ws + (28u << 20));  // 4 MB
    unsigned short* wT     = (unsigned short*)(ws + (32u << 20));  // 8 MB transposed weight
    unsigned short* vecs   = (unsigned short*)(ws + (40u << 20));  // 80 KB canonical vecs
    int*            flag   = (int*)(ws + (40u << 20) + (128u << 10));

    sniff_kernel<<<1, 256, 0, stream>>>((const unsigned short*)x, flag);

    conv_vec<<<16, 256, 0, stream>>>(ln1_g, vecs + 0,    1024, flag);
    conv_vec<<<16, 256, 0, stream>>>(ln1_b, vecs + 1024, 1024, flag);
    conv_vec<<<16, 256, 0, stream>>>(out_b, vecs + 2048, 1024, flag);
    conv_vec<<<16, 256, 0, stream>>>(ln2_g, vecs + 3072, 1024, flag);
    conv_vec<<<16, 256, 0, stream>>>(ln2_b, vecs + 4096, 1024, flag);
    conv_vec<<<16, 256, 0, stream>>>(ff2_b, vecs + 5120, 1024, flag);
    conv_vec<<<64, 256, 0, stream>>>(ff1_b, vecs + 6144, 4096, flag);

    const int nx = MROWS * DIMM;  // 2M
    cvt_x<<<nx / 256, 256, 0, stream>>>(x, xf, flag);

    for (int l = 0; l < DEPTHN; l++) {
        const unsigned short* lv = vecs + l * VSTR;
        // --- attention half ---
        ln_kernel<<<MROWS, 256, 0, stream>>>(xf, lv + 0, lv + 1024, h_bf);
        transpose_conv<<<dim3(3072 / 32, 1024 / 32), dim3(32, 8), 0, stream>>>(
            qkv_w, (size_t)l * 1024 * 3072, wT, 1024, 3072, flag);
        gemm_bt<0><<<dim3(3072 / 128, MROWS / 128), 256, 0, stream>>>(
            h_bf, wT, nullptr, qkv_bf, nullptr, MROWS, 3072, 1024);
        attn_kernel<<<BB * HEADSN * (NSEQ / 4), 256, 0, stream>>>(qkv_bf, mask, o_bf);
        transpose_conv<<<dim3(1024 / 32, 1024 / 32), dim3(32, 8), 0, stream>>>(
            out_w, (size_t)l * 1024 * 1024, wT, 1024, 1024, flag);
        gemm_bt<1><<<dim3(1024 / 128, MROWS / 128), 256, 0, stream>>>(
            o_bf, wT, lv + 2048, nullptr, xf, MROWS, 1024, 1024);
        // --- feedforward half ---
        ln_kernel<<<MROWS, 256, 0, stream>>>(xf, lv + 3072, lv + 4096, h_bf);
        transpose_conv<<<dim3(4096 / 32, 1024 / 32), dim3(32, 8), 0, stream>>>(
            ff1_w, (size_t)l * 1024 * 4096, wT, 1024, 4096, flag);
        gemm_bt<2><<<dim3(4096 / 128, MROWS / 128), 256, 0, stream>>>(
            h_bf, wT, lv + 6144, ff_bf, nullptr, MROWS, 4096, 1024);
        transpose_conv<<<dim3(1024 / 32, 4096 / 32), dim3(32, 8), 0, stream>>>(
            ff2_w, (size_t)l * 4096 * 1024, wT, 4096, 1024, flag);
        gemm_bt<1><<<dim3(1024 / 128, MROWS / 128), 256, 0, stream>>>(
            ff_bf, wT, lv + 5120, nullptr, xf, MROWS, 1024, 4096);
    }

    store_out<<<nx / 256, 256, 0, stream>>>(xf, d_out, flag);
}

// Round 3
// 1224.317 us; speedup vs baseline: 3.0226x; 3.0226x over previous
//
#include <hip/hip_runtime.h>
#include <stdint.h>

#define DIMM 1024
#define NSEQ 1024
#define BB 2
#define HEADSN 16
#define MLPD 4096
#define DEPTHN 4
#define MROWS (BB*NSEQ)  // 2048
#define VSTR 10240       // canonical per-layer vec stride (elements)

typedef __bf16 bf16x8 __attribute__((ext_vector_type(8)));
typedef float f32x4 __attribute__((ext_vector_type(4)));

__device__ __forceinline__ float bf2f(unsigned short u) {
    union { uint32_t i; float f; } x; x.i = ((uint32_t)u) << 16; return x.f;
}
__device__ __forceinline__ unsigned short f2bf(float f) {
    union { uint32_t i; float f; } x; x.f = f;
    uint32_t r = x.i + 0x7fffu + ((x.i >> 16) & 1u);
    return (unsigned short)(r >> 16);
}
__device__ __forceinline__ float loadf(const void* p, size_t i, int f32) {
    return f32 ? ((const float*)p)[i] : bf2f(((const unsigned short*)p)[i]);
}

// ---------------- dtype sniff ----------------
__global__ __launch_bounds__(256) void sniff_kernel(const unsigned short* __restrict__ x,
                                                    int* __restrict__ flag) {
    __shared__ int cnt[256];
    int tid = threadIdx.x;
    int c = 0;
    for (int i = tid * 2; i < 65536; i += 512) {
        int e = (x[i] >> 7) & 0xFF;
        if (e >= 0x8A) c++;
    }
    cnt[tid] = c;
    __syncthreads();
    for (int s = 128; s > 0; s >>= 1) {
        if (tid < s) cnt[tid] += cnt[tid + s];
        __syncthreads();
    }
    if (tid == 0) flag[0] = (cnt[0] > 32) ? 1 : 0;
}

// ---------------- converts ----------------
__global__ __launch_bounds__(256) void cvt_x(const void* __restrict__ x, float* __restrict__ xf,
                                             const int* __restrict__ flag) {
    int f = flag[0];
    int i = blockIdx.x * 256 + threadIdx.x;
    xf[i] = loadf(x, i, f);
}
__global__ __launch_bounds__(256) void store_out(const float* __restrict__ xf, void* __restrict__ out,
                                                 const int* __restrict__ flag) {
    int f = flag[0];
    int i = blockIdx.x * 256 + threadIdx.x;
    float v = xf[i];
    if (f) ((float*)out)[i] = v;
    else   ((unsigned short*)out)[i] = f2bf(v);
}
__global__ __launch_bounds__(256) void conv_vec(const void* __restrict__ src,
                                                unsigned short* __restrict__ dst,
                                                int len, const int* __restrict__ flag) {
    int f = flag[0];
    int i = blockIdx.x * 256 + threadIdx.x;
    if (i < DEPTHN * len) {
        int l = i / len, o = i - l * len;
        dst[l * VSTR + o] = f2bf(loadf(src, i, f));
    }
}

// ---------------- transpose+convert: src[srcOffE + k*N + n] -> bf16 out[n*K + k] ----------------
__global__ __launch_bounds__(256) void transpose_conv(const void* __restrict__ in, size_t srcOffE,
                                                      unsigned short* __restrict__ out,
                                                      int K, int N, const int* __restrict__ flag) {
    int f = flag[0];
    __shared__ unsigned short t[32][33];
    int n0 = blockIdx.x * 32, k0 = blockIdx.y * 32;
    int tx = threadIdx.x, ty = threadIdx.y;  // 32 x 8
#pragma unroll
    for (int i = 0; i < 4; i++) {
        int k = k0 + ty + i * 8;
        t[ty + i * 8][tx] = f2bf(loadf(in, srcOffE + (size_t)k * N + n0 + tx, f));
    }
    __syncthreads();
#pragma unroll
    for (int i = 0; i < 4; i++) {
        int n = n0 + ty + i * 8;
        out[(size_t)n * K + k0 + tx] = t[tx][ty + i * 8];
    }
}

// ---------------- V^T per layer: qkv[b*1024+k][2048 + c] -> vt[(b*16h..)*64+d][k] ----------------
__global__ __launch_bounds__(256) void vt_kernel(const unsigned short* __restrict__ qkv,
                                                 unsigned short* __restrict__ vt) {
    __shared__ unsigned short t[32][33];
    int b = blockIdx.z;
    int c0 = blockIdx.x * 32, k0 = blockIdx.y * 32;
    int tx = threadIdx.x, ty = threadIdx.y;  // 32 x 8
#pragma unroll
    for (int i = 0; i < 4; i++) {
        int k = k0 + ty + i * 8;
        t[ty + i * 8][tx] = qkv[(size_t)(b * 1024 + k) * 3072 + 2048 + c0 + tx];
    }
    __syncthreads();
#pragma unroll
    for (int i = 0; i < 4; i++) {
        int c = c0 + ty + i * 8;
        vt[(size_t)(b * 1024 + c) * 1024 + k0 + tx] = t[tx][ty + i * 8];
    }
}

// ---------------- mask -> bitmask u64 words ----------------
__global__ __launch_bounds__(256) void mask_pack(const int* __restrict__ mask,
                                                 unsigned long long* __restrict__ bits) {
    int wid = (blockIdx.x * 256 + threadIdx.x) >> 6;  // 2048 waves
    int lane = threadIdx.x & 63;
#pragma unroll
    for (int i = 0; i < 16; i++) {
        int w = wid * 16 + i;  // 32768 words total
        int mv = mask[(size_t)w * 64 + lane];
        unsigned long long bl = __ballot(mv != 0);
        if (lane == 0) bits[w] = bl;
    }
}

// ---------------- LayerNorm ----------------
__global__ __launch_bounds__(256) void ln_kernel(const float* __restrict__ x,
                                                 const unsigned short* __restrict__ g,
                                                 const unsigned short* __restrict__ bta,
                                                 unsigned short* __restrict__ out) {
    int row = blockIdx.x, tid = threadIdx.x;
    const float* xr = x + (size_t)row * DIMM;
    float v[4]; float s = 0.f, s2 = 0.f;
#pragma unroll
    for (int i = 0; i < 4; i++) { v[i] = xr[tid + i * 256]; s += v[i]; s2 += v[i] * v[i]; }
#pragma unroll
    for (int off = 32; off >= 1; off >>= 1) {
        s  += __shfl_down(s, off, 64);
        s2 += __shfl_down(s2, off, 64);
    }
    __shared__ float rs[4], rs2[4];
    int wv = tid >> 6;
    if ((tid & 63) == 0) { rs[wv] = s; rs2[wv] = s2; }
    __syncthreads();
    s  = rs[0] + rs[1] + rs[2] + rs[3];
    s2 = rs2[0] + rs2[1] + rs2[2] + rs2[3];
    float mu  = s * (1.f / DIMM);
    float var = s2 * (1.f / DIMM) - mu * mu;
    float rr  = rsqrtf(var + 1e-5f);
#pragma unroll
    for (int i = 0; i < 4; i++) {
        int c = tid + i * 256;
        float y = (v[i] - mu) * rr * bf2f(g[c]) + bf2f(bta[c]);
        out[(size_t)row * DIMM + c] = f2bf(y);
    }
}

// ---------------- GEMM: A[M,K] bf16 x Bt[N,K] bf16 -> epilogue ----------------
template <int MODE>
__global__ __launch_bounds__(256) void gemm_bt(const unsigned short* __restrict__ A,
                                               const unsigned short* __restrict__ Bt,
                                               const unsigned short* __restrict__ bias,
                                               unsigned short* __restrict__ Cbf,
                                               float* __restrict__ Cres,
                                               int M, int N, int K) {
    __shared__ unsigned short As[128 * 32];
    __shared__ unsigned short Bs[128 * 32];
    const int tid = threadIdx.x;
    const int mBase = blockIdx.y * 128, nBase = blockIdx.x * 128;
    const int w = tid >> 6, lane = tid & 63;
    const int wm = (w >> 1) * 64, wn = (w & 1) * 64;
    const int quad = lane >> 4, l16 = lane & 15;
    f32x4 acc[4][4];
#pragma unroll
    for (int i = 0; i < 4; i++)
#pragma unroll
        for (int j = 0; j < 4; j++) acc[i][j] = (f32x4){0.f, 0.f, 0.f, 0.f};

    const int sRow = tid >> 1, sCol = (tid & 1) * 16;
    const unsigned short* Ag = A + (size_t)(mBase + sRow) * K + sCol;
    const unsigned short* Bg = Bt + (size_t)(nBase + sRow) * K + sCol;

    uint4 ra0 = *(const uint4*)(Ag);
    uint4 ra1 = *(const uint4*)(Ag + 8);
    uint4 rb0 = *(const uint4*)(Bg);
    uint4 rb1 = *(const uint4*)(Bg + 8);

    for (int k0 = 0; k0 < K; k0 += 32) {
        __syncthreads();
        *(uint4*)&As[sRow * 32 + sCol]     = ra0;
        *(uint4*)&As[sRow * 32 + sCol + 8] = ra1;
        *(uint4*)&Bs[sRow * 32 + sCol]     = rb0;
        *(uint4*)&Bs[sRow * 32 + sCol + 8] = rb1;
        __syncthreads();
        if (k0 + 32 < K) {
            ra0 = *(const uint4*)(Ag + k0 + 32);
            ra1 = *(const uint4*)(Ag + k0 + 40);
            rb0 = *(const uint4*)(Bg + k0 + 32);
            rb1 = *(const uint4*)(Bg + k0 + 40);
        }
        bf16x8 af[4], bfv[4];
#pragma unroll
        for (int i = 0; i < 4; i++)
            af[i] = *(const bf16x8*)&As[(wm + i * 16 + l16) * 32 + quad * 8];
#pragma unroll
        for (int j = 0; j < 4; j++)
            bfv[j] = *(const bf16x8*)&Bs[(wn + j * 16 + l16) * 32 + quad * 8];
#pragma unroll
        for (int i = 0; i < 4; i++)
#pragma unroll
            for (int j = 0; j < 4; j++)
                acc[i][j] = __builtin_amdgcn_mfma_f32_16x16x32_bf16(af[i], bfv[j], acc[i][j], 0, 0, 0);
    }

#pragma unroll
    for (int i = 0; i < 4; i++) {
#pragma unroll
        for (int j = 0; j < 4; j++) {
#pragma unroll
            for (int r = 0; r < 4; r++) {
                int m = mBase + wm + i * 16 + quad * 4 + r;
                int n = nBase + wn + j * 16 + l16;
                float v = acc[i][j][r];
                size_t idx = (size_t)m * N + n;
                if (MODE == 0) {
                    Cbf[idx] = f2bf(v);
                } else if (MODE == 1) {
                    Cres[idx] += v + bf2f(bias[n]);
                } else {
                    float t2 = v + bf2f(bias[n]);
                    float gg = 0.5f * t2 * (1.f + erff(t2 * 0.70710678118f));
                    Cbf[idx] = f2bf(gg);
                }
            }
        }
    }
}

// ---------------- MFMA flash attention ----------------
// Block: 64 q-rows of one (b,h); 4 waves x 16 rows. K tiles of 64 keys.
// Ks: [key][d] stride 72  (B-frag for QK^T: contiguous d = contraction)
// Vs: [d][key] stride 72  (B-frag for PV:   contiguous key = contraction; from pre-transposed vt)
// Ps: per-wave [16 q][64 key] stride 68 (A-frag for PV)
__global__ __launch_bounds__(256) void attn_mfma(const unsigned short* __restrict__ qkv,
                                                 const unsigned short* __restrict__ vt,
                                                 const unsigned long long* __restrict__ mbits,
                                                 unsigned short* __restrict__ o) {
    __shared__ unsigned short Ks[64 * 72];
    __shared__ unsigned short Vs[64 * 72];
    __shared__ unsigned short Ps[4][16 * 68];

    const int tid = threadIdx.x, w = tid >> 6, lane = tid & 63;
    const int quad = lane >> 4, l16 = lane & 15;
    const int qt = blockIdx.x, h = blockIdx.y, b = blockIdx.z;

    // Q fragments in registers (A-operand: lane holds Q[row=l16][d=quad*8+j])
    const size_t qrow = (size_t)(b * NSEQ + qt * 64 + w * 16 + l16) * 3072 + h * 64;
    bf16x8 qf[2];
    qf[0] = *(const bf16x8*)(qkv + qrow + quad * 8);
    qf[1] = *(const bf16x8*)(qkv + qrow + 32 + quad * 8);

    // staging mapping: 256 threads x 32B = 8KB tile
    const int srow = tid >> 2, scol = (tid & 3) * 16;
    const unsigned short* kg_base = qkv + (size_t)(b * NSEQ) * 3072 + 1024 + h * 64;
    const unsigned short* vg_base = vt + (size_t)((b * HEADSN + h) * 64 + srow) * 1024;

    f32x4 oacc[4];
#pragma unroll
    for (int j = 0; j < 4; j++) oacc[j] = (f32x4){0.f, 0.f, 0.f, 0.f};
    float m_run[4], l_run[4];
#pragma unroll
    for (int r = 0; r < 4; r++) { m_run[r] = -1e30f; l_run[r] = 0.f; }

    // mask bit-words for this lane's 4 rows
    const unsigned long long* mb =
        mbits + ((size_t)(b * NSEQ + qt * 64 + w * 16 + quad * 4)) * 16;

    for (int kt = 0; kt < 16; kt++) {
        __syncthreads();
        {
            const unsigned short* kg = kg_base + (size_t)(kt * 64 + srow) * 3072 + scol;
            uint4 k0 = *(const uint4*)kg;
            uint4 k1 = *(const uint4*)(kg + 8);
            const unsigned short* vg = vg_base + kt * 64 + scol;
            uint4 v0 = *(const uint4*)vg;
            uint4 v1 = *(const uint4*)(vg + 8);
            *(uint4*)&Ks[srow * 72 + scol]     = k0;
            *(uint4*)&Ks[srow * 72 + scol + 8] = k1;
            *(uint4*)&Vs[srow * 72 + scol]     = v0;
            *(uint4*)&Vs[srow * 72 + scol + 8] = v1;
        }
        __syncthreads();

        // --- S = Q K^T (scaled later), C-layout: row=quad*4+r, col=j*16+l16 ---
        f32x4 sacc[4];
#pragma unroll
        for (int j = 0; j < 4; j++) sacc[j] = (f32x4){0.f, 0.f, 0.f, 0.f};
#pragma unroll
        for (int ks = 0; ks < 2; ks++) {
#pragma unroll
            for (int j = 0; j < 4; j++) {
                bf16x8 kf = *(const bf16x8*)&Ks[(j * 16 + l16) * 72 + ks * 32 + quad * 8];
                sacc[j] = __builtin_amdgcn_mfma_f32_16x16x32_bf16(qf[ks], kf, sacc[j], 0, 0, 0);
            }
        }

        // --- mask + online softmax ---
        unsigned long long mw[4];
#pragma unroll
        for (int r = 0; r < 4; r++) mw[r] = mb[r * 16 + kt];

        float sv[4][4];  // [j][r]
        float tmax[4];
#pragma unroll
        for (int r = 0; r < 4; r++) {
            float mx = -1e30f;
#pragma unroll
            for (int j = 0; j < 4; j++) {
                float t = sacc[j][r] * 0.125f;
                int keep = (int)((mw[r] >> (j * 16 + l16)) & 1ull);
                t = keep ? t : -1e9f;
                sv[j][r] = t;
                mx = fmaxf(mx, t);
            }
#pragma unroll
            for (int off = 1; off < 16; off <<= 1)
                mx = fmaxf(mx, __shfl_xor(mx, off, 64));
            tmax[r] = mx;
        }
#pragma unroll
        for (int r = 0; r < 4; r++) {
            float m_new = fmaxf(m_run[r], tmax[r]);
            float alpha = __expf(m_run[r] - m_new);
            m_run[r] = m_new;
            float pj[4], ps = 0.f;
#pragma unroll
            for (int j = 0; j < 4; j++) {
                pj[j] = __expf(sv[j][r] - m_new);
                ps += pj[j];
            }
#pragma unroll
            for (int off = 1; off < 16; off <<= 1)
                ps += __shfl_xor(ps, off, 64);
            l_run[r] = l_run[r] * alpha + ps;
#pragma unroll
            for (int j = 0; j < 4; j++) {
                oacc[j][r] *= alpha;
                Ps[w][(quad * 4 + r) * 68 + j * 16 + l16] = f2bf(pj[j]);
            }
        }

        // --- O += P V  (A-frag from Ps, B-frag from Vs) ---
#pragma unroll
        for (int ks = 0; ks < 2; ks++) {
            const unsigned short* pr = &Ps[w][l16 * 68 + ks * 32 + quad * 8];
            union { ushort4 u[2]; bf16x8 v; } af;
            af.u[0] = *(const ushort4*)pr;        // 8B-aligned
            af.u[1] = *(const ushort4*)(pr + 4);
#pragma unroll
            for (int j = 0; j < 4; j++) {
                bf16x8 vf = *(const bf16x8*)&Vs[(j * 16 + l16) * 72 + ks * 32 + quad * 8];
                oacc[j] = __builtin_amdgcn_mfma_f32_16x16x32_bf16(af.v, vf, oacc[j], 0, 0, 0);
            }
        }
    }

    // epilogue: O row quad*4+r, col j*16+l16
#pragma unroll
    for (int j = 0; j < 4; j++) {
#pragma unroll
        for (int r = 0; r < 4; r++) {
            size_t row = (size_t)(b * NSEQ + qt * 64 + w * 16 + quad * 4 + r);
            o[row * 1024 + h * 64 + j * 16 + l16] = f2bf(oacc[j][r] / l_run[r]);
        }
    }
}

extern "C" void kernel_launch(void* const* d_in, const int* in_sizes, int n_in,
                              void* d_out, int out_size, void* d_ws, size_t ws_size,
                              hipStream_t stream) {
    const void* x     = d_in[0];
    const int*  mask  = (const int*)d_in[1];
    const void* ln1_g = d_in[2];
    const void* ln1_b = d_in[3];
    const void* qkv_w = d_in[4];
    const void* out_w = d_in[5];
    const void* out_b = d_in[6];
    const void* ln2_g = d_in[7];
    const void* ln2_b = d_in[8];
    const void* ff1_w = d_in[9];
    const void* ff1_b = d_in[10];
    const void* ff2_w = d_in[11];
    const void* ff2_b = d_in[12];

    char* ws = (char*)d_ws;
    float*          xf     = (float*)ws;                            // 8 MB fp32 residual
    unsigned short* h_bf   = (unsigned short*)(ws + (8u  << 20));   // 4 MB LN out
    unsigned short* qkv_bf = (unsigned short*)(ws + (12u << 20));   // 12 MB (attn half)
    unsigned short* ff_bf  = (unsigned short*)(ws + (12u << 20));   // 16 MB (ff half, reuses qkv+vt)
    unsigned short* vt_bf  = (unsigned short*)(ws + (24u << 20));   // 4 MB V^T (attn half)
    unsigned short* o_bf   = (unsigned short*)(ws + (28u << 20));   // 4 MB
    unsigned short* wT     = (unsigned short*)(ws + (32u << 20));   // 8 MB transposed weight
    unsigned short* vecs   = (unsigned short*)(ws + (40u << 20));   // 80 KB canonical vecs
    int*            flag   = (int*)(ws + (40u << 20) + (128u << 10));
    unsigned long long* mbits = (unsigned long long*)(ws + (40u << 20) + (192u << 10)); // 256 KB

    sniff_kernel<<<1, 256, 0, stream>>>((const unsigned short*)x, flag);

    conv_vec<<<16, 256, 0, stream>>>(ln1_g, vecs + 0,    1024, flag);
    conv_vec<<<16, 256, 0, stream>>>(ln1_b, vecs + 1024, 1024, flag);
    conv_vec<<<16, 256, 0, stream>>>(out_b, vecs + 2048, 1024, flag);
    conv_vec<<<16, 256, 0, stream>>>(ln2_g, vecs + 3072, 1024, flag);
    conv_vec<<<16, 256, 0, stream>>>(ln2_b, vecs + 4096, 1024, flag);
    conv_vec<<<16, 256, 0, stream>>>(ff2_b, vecs + 5120, 1024, flag);
    conv_vec<<<64, 256, 0, stream>>>(ff1_b, vecs + 6144, 4096, flag);

    mask_pack<<<512, 256, 0, stream>>>(mask, mbits);

    const int nx = MROWS * DIMM;  // 2M
    cvt_x<<<nx / 256, 256, 0, stream>>>(x, xf, flag);

    for (int l = 0; l < DEPTHN; l++) {
        const unsigned short* lv = vecs + l * VSTR;
        // --- attention half ---
        ln_kernel<<<MROWS, 256, 0, stream>>>(xf, lv + 0, lv + 1024, h_bf);
        transpose_conv<<<dim3(3072 / 32, 1024 / 32), dim3(32, 8), 0, stream>>>(
            qkv_w, (size_t)l * 1024 * 3072, wT, 1024, 3072, flag);
        gemm_bt<0><<<dim3(3072 / 128, MROWS / 128), 256, 0, stream>>>(
            h_bf, wT, nullptr, qkv_bf, nullptr, MROWS, 3072, 1024);
        vt_kernel<<<dim3(32, 32, BB), dim3(32, 8), 0, stream>>>(qkv_bf, vt_bf);
        attn_mfma<<<dim3(NSEQ / 64, HEADSN, BB), 256, 0, stream>>>(qkv_bf, vt_bf, mbits, o_bf);
        transpose_conv<<<dim3(1024 / 32, 1024 / 32), dim3(32, 8), 0, stream>>>(
            out_w, (size_t)l * 1024 * 1024, wT, 1024, 1024, flag);
        gemm_bt<1><<<dim3(1024 / 128, MROWS / 128), 256, 0, stream>>>(
            o_bf, wT, lv + 2048, nullptr, xf, MROWS, 1024, 1024);
        // --- feedforward half ---
        ln_kernel<<<MROWS, 256, 0, stream>>>(xf, lv + 3072, lv + 4096, h_bf);
        transpose_conv<<<dim3(4096 / 32, 1024 / 32), dim3(32, 8), 0, stream>>>(
            ff1_w, (size_t)l * 1024 * 4096, wT, 1024, 4096, flag);
        gemm_bt<2><<<dim3(4096 / 128, MROWS / 128), 256, 0, stream>>>(
            h_bf, wT, lv + 6144, ff_bf, nullptr, MROWS, 4096, 1024);
        transpose_conv<<<dim3(1024 / 32, 4096 / 32), dim3(32, 8), 0, stream>>>(
            ff2_w, (size_t)l * 4096 * 1024, wT, 4096, 1024, flag);
        gemm_bt<1><<<dim3(1024 / 128, MROWS / 128), 256, 0, stream>>>(
            ff_bf, wT, lv + 5120, nullptr, xf, MROWS, 1024, 4096);
    }

    store_out<<<nx / 256, 256, 0, stream>>>(xf, d_out, flag);
}